// Round 5
// baseline (135.599 us; speedup 1.0000x reference)
//
#include <hip/hip_runtime.h>

// ---------------------------------------------------------------------------
// SocialPooling: pooled = per-person 8x8-grid scatter-add of neighbor hiddens,
// out = relu(pooled @ W + b).  M=B=4096, K=4096, N=1024.
// R5: GEMM 128x128 block, 4 waves (2x2) each 64x64 (2x2 of 32x32x16 MFMA) --
// 1.5x less LDS read traffic per FLOP (the measured bottleneck).  BK=64 with
// explicit LDS double-buffer (64 KB), one barrier/iter: at 1 block/CU the
// prefetch drain hides behind ~1100 cyc of compute.  XCD m-clustered map.
// ---------------------------------------------------------------------------

#define BM 128
#define BN 128
#define BK 64    // shorts (bf16) per K-block per buffer

typedef short short8 __attribute__((ext_vector_type(8)));
typedef short short4v __attribute__((ext_vector_type(4)));
typedef float floatx16 __attribute__((ext_vector_type(16)));

__device__ inline short f2bf(float x) {
    union { float f; unsigned u; } v; v.f = x;
    unsigned r = v.u + 0x7fffu + ((v.u >> 16) & 1u);   // round-to-nearest-even
    return (short)(r >> 16);
}

__device__ inline void gload_lds16(const void* g, void* l) {
    __builtin_amdgcn_global_load_lds(
        (const __attribute__((address_space(1))) void*)g,
        (__attribute__((address_space(3))) void*)l,
        16, 0, 0);
}

// ---------------------------------------------------------------------------
// Kernel 1: prep = pool (blocks 0..1023) + W transpose/cast (blocks 1024..2047)
// merged so the two independent stages run concurrently.  (R2-proven.)
// ---------------------------------------------------------------------------
__global__ __launch_bounds__(256) void prep_kernel(
    const float* __restrict__ h,     // (B, 64)
    const float* __restrict__ pos,   // (B, 2)
    short* __restrict__ pooled,      // (B, 4096) bf16
    const float* __restrict__ W,     // (K, N)
    short* __restrict__ Wt,          // (N, K) bf16
    int K, int N, int poolBlocks)
{
    __shared__ __align__(16) unsigned char sh[18944];
    const int tid = threadIdx.x;

    if ((int)blockIdx.x < poolBlocks) {
        // ----- pooling: 4 persons of one sequence per block -----
        float* hs = (float*)sh;                          // 64*64 f32 = 16 KB
        float* px = (float*)(sh + 16384);
        float* py = (float*)(sh + 16640);
        unsigned long long* wmask = (unsigned long long*)(sh + 16896); // 4*64

        const int lane = tid & 63;
        const int w    = tid >> 6;
        const int s    = blockIdx.x >> 4;
        const int grp  = blockIdx.x & 15;
        const size_t base = (size_t)s * 64;

        const float4* hv  = (const float4*)(h + base * 64);
        float4*       hsv = (float4*)hs;
        #pragma unroll
        for (int c = 0; c < 4; ++c) hsv[tid + c * 256] = hv[tid + c * 256];
        if (tid < 64) {
            float2 p = ((const float2*)pos)[base + tid];
            px[tid] = p.x; py[tid] = p.y;
        }
        wmask[w * 64 + lane] = 0ull;
        __syncthreads();

        const int i = grp * 4 + w;
        const float tlx = px[i] - 1.0f;
        const float tly = py[i] + 1.0f;
        const float brx = px[i] + 1.0f;
        const float bry = py[i] - 1.0f;

        {   // lane j: neighbor j's cell for person i (wave-local)
            const int j = lane;
            const float ox = px[j], oy = py[j];
            if (ox < brx && ox > tlx && oy < tly && oy > bry && j != i) {
                int cx = (int)floorf((ox - tlx) * 4.0f);
                int cy = (int)floorf((tly - oy) * 4.0f);
                atomicOr(&wmask[w * 64 + cx + cy * 8], 1ull << j);
            }
        }

        const int d = lane;
        const size_t orow = (base + i) * 4096;
        for (int c = 0; c < 64; ++c) {
            unsigned long long m = wmask[w * 64 + c];
            float a0 = 0.f, a1 = 0.f;
            while (m) {
                int j0 = __builtin_ctzll(m); m &= m - 1;
                if (m) {
                    int j1 = __builtin_ctzll(m); m &= m - 1;
                    a1 += hs[j1 * 64 + d];
                }
                a0 += hs[j0 * 64 + d];
            }
            pooled[orow + c * 64 + d] = f2bf(a0 + a1);
        }
    } else {
        // ----- W (K x N f32) -> Wt (N x K bf16), 64x64 tiles -----
        float* t = (float*)sh;                 // [64][65]
        const int bid = blockIdx.x - poolBlocks;
        const int k0 = (bid & 63) * 64;
        const int n0 = (bid >> 6) * 64;

        const int r  = tid >> 4;               // 0..15
        const int cq = (tid & 15) * 4;
        #pragma unroll
        for (int i2 = 0; i2 < 4; ++i2) {
            const int row = r + i2 * 16;
            float4 v = *(const float4*)&W[(size_t)(k0 + row) * N + n0 + cq];
            t[row * 65 + cq + 0] = v.x; t[row * 65 + cq + 1] = v.y;
            t[row * 65 + cq + 2] = v.z; t[row * 65 + cq + 3] = v.w;
        }
        __syncthreads();
        const int nl = tid >> 4;
        const int kq = (tid & 15) * 4;
        #pragma unroll
        for (int i2 = 0; i2 < 4; ++i2) {
            const int n = nl + i2 * 16;
            short4v o;
            o.x = f2bf(t[(kq + 0) * 65 + n]); o.y = f2bf(t[(kq + 1) * 65 + n]);
            o.z = f2bf(t[(kq + 2) * 65 + n]); o.w = f2bf(t[(kq + 3) * 65 + n]);
            *(short4v*)&Wt[(size_t)(n0 + n) * K + k0 + kq] = o;
        }
    }
}

// ---------------------------------------------------------------------------
// Kernel 2: C = relu(A @ Bt^T + bias).  A: MxK bf16, Bt: NxK bf16.
// 128x128 block, 256 thr = 4 waves (2x2), wave tile 64x64 = 2x2 of 32x32x16.
// Explicit double-buffered LDS, BK=64, one barrier/iter.  XOR granule swizzle
// (8 granules/row; verified conflict-free pattern).  Grid 256, XCD m-cluster.
// ---------------------------------------------------------------------------
__global__ __launch_bounds__(256) void gemm_bias_relu(
    const short* __restrict__ A,
    const short* __restrict__ Bt,
    const float* __restrict__ bias,
    float* __restrict__ out,
    int M, int N, int K)
{
    // [buf][mat][128 rows * 64 shorts] = 2*2*16 KB = 64 KB
    __shared__ __align__(16) short smem[2][2][BM * BK];

    const int tid  = threadIdx.x;
    const int lane = tid & 63;
    const int wave = tid >> 6;          // 0..3
    const int wr = wave >> 1;           // wave row in 2x2
    const int wc = wave & 1;            // wave col
    const int nl = lane & 31;           // MFMA row/col within 32
    const int hl = lane >> 5;           // K-half
    const int k7 = nl & 7;              // read-side swizzle key (= row&7)

    // XCD m-clustered mapping: XCD x owns m-blocks 4x..4x+3; n fastest.
    const int b  = blockIdx.x;
    const int ib = b >> 3;                            // 0..31
    const int m0 = ((b & 7) * 4 + (ib >> 3)) * BM;    // m-block 0..31
    const int n0 = (ib & 7) * BN;                     // n-block 0..7

    // staging: wave-instr covers 8 rows x 8 granules; lane = (r8, slot3)
    const int r8    = lane >> 3;        // 0..7
    const int slot3 = lane & 7;

    const short* ag[4];
    const short* bg[4];
    #pragma unroll
    for (int c = 0; c < 4; ++c) {
        const int g  = c * 4 + wave;            // 8-row group 0..15
        const int rl = g * 8 + r8;              // 0..127
        ag[c] = A  + (size_t)(m0 + rl) * K + (slot3 ^ (rl & 7)) * 8;
        bg[c] = Bt + (size_t)(n0 + rl) * K + (slot3 ^ (rl & 7)) * 8;
    }

    floatx16 acc[2][2];
    #pragma unroll
    for (int i = 0; i < 2; ++i)
        #pragma unroll
        for (int j = 0; j < 2; ++j)
            #pragma unroll
            for (int r = 0; r < 16; ++r) acc[i][j][r] = 0.f;

    // prologue: stage first K-block into buf 0
    #pragma unroll
    for (int c = 0; c < 4; ++c) {
        gload_lds16(ag[c], &smem[0][0][(c * 4 + wave) * 512]);
        gload_lds16(bg[c], &smem[0][1][(c * 4 + wave) * 512]);
        ag[c] += BK; bg[c] += BK;
    }
    __syncthreads();

    for (int kb = 0; kb < K; kb += BK) {
        const int bu = (kb >> 6) & 1;
        if (kb + BK < K) {                 // prefetch next block into bu^1
            #pragma unroll
            for (int c = 0; c < 4; ++c) {
                gload_lds16(ag[c], &smem[bu ^ 1][0][(c * 4 + wave) * 512]);
                gload_lds16(bg[c], &smem[bu ^ 1][1][(c * 4 + wave) * 512]);
                ag[c] += BK; bg[c] += BK;
            }
        }
        // compute on bu
        #pragma unroll
        for (int t = 0; t < 4; ++t) {                  // 4 x K=16 steps
            const int g = 2 * t + hl;                  // needed granule
            const int go = (g ^ k7) * 8;               // swizzled offset (shorts)
            short8 a0 = *(const short8*)&smem[bu][0][(wr * 64 +      nl) * BK + go];
            short8 a1 = *(const short8*)&smem[bu][0][(wr * 64 + 32 + nl) * BK + go];
            short8 b0 = *(const short8*)&smem[bu][1][(wc * 64 +      nl) * BK + go];
            short8 b1 = *(const short8*)&smem[bu][1][(wc * 64 + 32 + nl) * BK + go];
            acc[0][0] = __builtin_amdgcn_mfma_f32_32x32x16_bf16(a0, b0, acc[0][0], 0, 0, 0);
            acc[0][1] = __builtin_amdgcn_mfma_f32_32x32x16_bf16(a0, b1, acc[0][1], 0, 0, 0);
            acc[1][0] = __builtin_amdgcn_mfma_f32_32x32x16_bf16(a1, b0, acc[1][0], 0, 0, 0);
            acc[1][1] = __builtin_amdgcn_mfma_f32_32x32x16_bf16(a1, b1, acc[1][1], 0, 0, 0);
        }
        __syncthreads();   // drains prefetch (issued before ~1100 cyc of compute)
    }

    // epilogue: bias + relu.  32x32 C/D: col=lane&31, row=(r&3)+8*(r>>2)+4*hl.
    #pragma unroll
    for (int jt = 0; jt < 2; ++jt) {
        const int gn = n0 + wc * 64 + jt * 32 + nl;
        const float bv = bias[gn];
        #pragma unroll
        for (int mt = 0; mt < 2; ++mt) {
            #pragma unroll
            for (int r = 0; r < 16; ++r) {
                const int row32 = (r & 3) + 8 * (r >> 2) + 4 * hl;
                const int gm = m0 + wr * 64 + mt * 32 + row32;
                float v = acc[mt][jt][r] + bv;
                out[(size_t)gm * N + gn] = v > 0.f ? v : 0.f;
            }
        }
    }
}

// ---------------------------------------------------------------------------
extern "C" void kernel_launch(void* const* d_in, const int* in_sizes, int n_in,
                              void* d_out, int out_size, void* d_ws, size_t ws_size,
                              hipStream_t stream) {
    const float* h    = (const float*)d_in[0];   // (1, B, 64) f32
    const float* pos  = (const float*)d_in[2];   // (B, 2)     f32
    const float* W    = (const float*)d_in[4];   // (K, N)     f32
    const float* bias = (const float*)d_in[5];   // (N,)       f32

    const int B = in_sizes[0] / 64;       // 4096
    const int N = in_sizes[5];            // 1024
    const int K = 64 * 64;                // GRID^2 * H_DIM = 4096

    short* pooled = (short*)d_ws;                  // B*K bf16 = 32 MB
    short* Wt     = pooled + (size_t)B * K;        // N*K bf16 =  8 MB
    float* out    = (float*)d_out;

    const int poolBlocks = B / 4;                  // 1024
    const int castBlocks = (K / 64) * (N / 64);    // 1024
    prep_kernel<<<poolBlocks + castBlocks, 256, 0, stream>>>(
        h, pos, pooled, W, Wt, K, N, poolBlocks);
    gemm_bias_relu<<<(B / BM) * (N / BN), 256, 0, stream>>>(
        pooled, Wt, bias, out, B, N, K);
}